// Round 8
// baseline (209.318 us; speedup 1.0000x reference)
//
#include <hip/hip_runtime.h>
#include <hip/hip_bf16.h>
#include <math.h>

#define T_TOK 2048
#define H_DIM 2048
#define E_EXP 16
#define I_DIM 512
#define TWO_I 1024
#define ROUTED_SCALE 1.5f
#define SWIGLU_LIMIT 7.0f

#define BM 128
#define KC 32
#define MAX_TILES 48
#define SLOTS 6144            // max padded assignment slots (4096 + 16*127 rounded)

typedef __attribute__((ext_vector_type(8))) short bf16x8;
typedef __attribute__((ext_vector_type(4))) float f32x4;
typedef unsigned short u16;

__device__ inline u16 f2bf(float f) {
    return __builtin_bit_cast(u16, __float2bfloat16(f));
}
__device__ inline ushort4 pack4(float4 a) {
    ushort4 v;
    v.x = f2bf(a.x); v.y = f2bf(a.y); v.z = f2bf(a.z); v.w = f2bf(a.w);
    return v;
}
__device__ inline bf16x8 cvt8(float4 a, float4 b) {
    bf16x8 v;
    v[0] = (short)f2bf(a.x); v[1] = (short)f2bf(a.y);
    v[2] = (short)f2bf(a.z); v[3] = (short)f2bf(a.w);
    v[4] = (short)f2bf(b.x); v[5] = (short)f2bf(b.y);
    v[6] = (short)f2bf(b.z); v[7] = (short)f2bf(b.w);
    return v;
}

// async 16B/lane global->LDS DMA
__device__ inline void gload16(const u16* g, u16* l) {
    __builtin_amdgcn_global_load_lds(
        (const __attribute__((address_space(1))) void*)(g),
        (__attribute__((address_space(3))) void*)(l), 16, 0, 0);
}
#define SCHED0() __builtin_amdgcn_sched_barrier(0)

// ---------------- router: one wave per token; also emits hs in bf16 ----------------
__global__ __launch_bounds__(256) void router_kernel(
    const float* __restrict__ hs, const float* __restrict__ gw,
    const float* __restrict__ bias, int* cnt, int* tok_list, float* w_list,
    u16* __restrict__ hs_bf)
{
    int wave = threadIdx.x >> 6;
    int lane = threadIdx.x & 63;
    int t = blockIdx.x * 4 + wave;
    if (t >= T_TOK) return;
    const float* x = hs + (size_t)t * H_DIM;

    float acc[E_EXP];
#pragma unroll
    for (int e = 0; e < E_EXP; ++e) acc[e] = 0.f;

#pragma unroll 2
    for (int c = 0; c < 8; ++c) {
        int col = c * 256 + lane * 4;
        float4 xv = *(const float4*)(x + col);
        *(ushort4*)(hs_bf + (size_t)t * H_DIM + col) = pack4(xv);
#pragma unroll
        for (int e = 0; e < E_EXP; ++e) {
            float4 gv = *(const float4*)(gw + (size_t)e * H_DIM + col);
            acc[e] = fmaf(xv.x, gv.x, acc[e]);
            acc[e] = fmaf(xv.y, gv.y, acc[e]);
            acc[e] = fmaf(xv.z, gv.z, acc[e]);
            acc[e] = fmaf(xv.w, gv.w, acc[e]);
        }
    }
#pragma unroll
    for (int e = 0; e < E_EXP; ++e) {
        for (int m = 32; m >= 1; m >>= 1)
            acc[e] += __shfl_xor(acc[e], m, 64);
    }
    if (lane == 0) {
        float sc[E_EXP], bsc[E_EXP];
#pragma unroll
        for (int e = 0; e < E_EXP; ++e) {
            sc[e] = 1.f / (1.f + expf(-acc[e]));
            bsc[e] = sc[e] + bias[e];
        }
        int e0 = 0; float b0 = bsc[0];
#pragma unroll
        for (int e = 1; e < E_EXP; ++e) if (bsc[e] > b0) { b0 = bsc[e]; e0 = e; }
        int e1 = -1; float b1 = -1e30f;
#pragma unroll
        for (int e = 0; e < E_EXP; ++e) {
            if (e == e0) continue;
            if (bsc[e] > b1) { b1 = bsc[e]; e1 = e; }
        }
        float s0 = sc[e0], s1 = sc[e1];
        float inv = ROUTED_SCALE / (s0 + s1);
        int p0 = atomicAdd(&cnt[e0], 1);
        tok_list[e0 * T_TOK + p0] = t;
        w_list[e0 * T_TOK + p0] = s0 * inv;
        int p1 = atomicAdd(&cnt[e1], 1);
        tok_list[e1 * T_TOK + p1] = t;
        w_list[e1 * T_TOK + p1] = s1 * inv;
    }
}

// ---------------- fused: compact assignments + tile descriptors (BM=128) ----------------
__global__ void scatter_build(const int* __restrict__ cnt,
    const int* __restrict__ tok_list, const float* __restrict__ w_list,
    int* A_tok, float* A_w, int* tile_e, int* tile_r0)
{
    int c[E_EXP], offs[E_EXP + 1];
    offs[0] = 0;
#pragma unroll
    for (int e = 0; e < E_EXP; ++e) {
        c[e] = cnt[e];
        offs[e + 1] = offs[e] + ((c[e] + BM - 1) & ~(BM - 1));
    }
    int idx = blockIdx.x * 256 + threadIdx.x;
    int e = idx >> 11;
    int pos = idx & (T_TOK - 1);
    int ce = c[e];
    int pe = (ce + BM - 1) & ~(BM - 1);
    if (pos < ce) {
        A_tok[offs[e] + pos] = tok_list[idx];
        A_w[offs[e] + pos] = w_list[idx];
    } else if (pos < pe) {
        A_tok[offs[e] + pos] = -1;
        A_w[offs[e] + pos] = 0.f;
    }
    if (idx == 0) {
        int nt = 0;
        for (int ee = 0; ee < E_EXP; ++ee) {
            int ntile = (c[ee] + BM - 1) >> 7;
            for (int j = 0; j < ntile; ++j) {
                tile_e[nt] = ee;
                tile_r0[nt] = offs[ee] + j * BM;
                ++nt;
            }
        }
        for (; nt < MAX_TILES; ++nt) tile_e[nt] = -1;
    }
}

// ---------------- GEMM1 (K-split x2): partial G/U sums -> gu_part fp32 ----------------
// grid 768: y = b&7 (XCD-pinned i-stripe), kspl = (b>>3)&1, tile = b>>4
__global__ __launch_bounds__(256, 3) void gemm1_gu(
    const u16* __restrict__ hs_bf, const float* __restrict__ w13,
    const int* __restrict__ A_tok, const int* __restrict__ tile_e,
    const int* __restrict__ tile_r0, float* __restrict__ gu_part)
{
    int b = blockIdx.x;
    int y = b & 7;
    int kspl = (b >> 3) & 1;
    int tile = b >> 4;
    int e = tile_e[tile];
    if (e < 0) return;
    int row0 = tile_r0[tile];
    int i0 = y * 64;
    int k0base = kspl * (H_DIM / 2);
    int tid = threadIdx.x;

    __shared__ u16 Xs[2][4096];   // 128 x 32 bf16
    __shared__ u16 Gs[2][2048];   // 64 x 32 bf16
    __shared__ u16 Us[2][2048];

    const int l = tid & 63, w = tid >> 6;

    // ---- X staging via global_load_lds (pre-swizzled source, linear dest) ----
    const u16* sX[2]; int dX[2];
#pragma unroll
    for (int j = 0; j < 2; ++j) {
        int row = w * 32 + j * 16 + (l >> 2);
        int tk = A_tok[row0 + row]; if (tk < 0) tk = 0;   // pad rows masked by A_w=0 downstream
        int sg = (l & 3) ^ ((l >> 3) & 3);
        sX[j] = hs_bf + (size_t)tk * H_DIM + k0base + sg * 8;
        dX[j] = (w * 32 + j * 16) * 32;
    }
#define X_STAGE(bb, t) do { int ko = (t) * KC; \
    gload16(sX[0] + ko, &Xs[bb][dX[0]]); gload16(sX[1] + ko, &Xs[bb][dX[1]]); } while (0)

    // ---- weight staging: dense fp32 loads -> regs -> bf16 -> swizzled ds_write ----
    const int wr = tid >> 2;              // 0..63
    const int wg = tid & 3;               // dest granule
    const int wsk = (wg ^ ((wr >> 1) & 3)) * 8;   // swizzled source k
    const float* gsrc = w13 + ((size_t)e * TWO_I + i0 + wr) * H_DIM + k0base + wsk;
    const float* usrc = gsrc + (size_t)I_DIM * H_DIM;
    const int wdst = wr * 32 + wg * 8;

    float4 gA, gB, uA, uB;
#define W_LOAD(t) do { int ko = (t) * KC; \
    gA = *(const float4*)(gsrc + ko); gB = *(const float4*)(gsrc + ko + 4); \
    uA = *(const float4*)(usrc + ko); uB = *(const float4*)(usrc + ko + 4); } while (0)
#define W_WRITE(bb) do { \
    *(bf16x8*)&Gs[bb][wdst] = cvt8(gA, gB); \
    *(bf16x8*)&Us[bb][wdst] = cvt8(uA, uB); } while (0)

    // ---- MFMA roles: 4 waves 2x2; wave tile 64 tok x 32 cols; 4m x 2n frags ----
    const int wm = w >> 1, wn = w & 1;
    const int lr = l & 15, lg = l >> 4;
    const int swz = (lg ^ ((lr >> 1) & 3)) * 8;
    int ix[4], ib[2];
#pragma unroll
    for (int m = 0; m < 4; ++m) ix[m] = (wm * 64 + m * 16 + lr) * 32 + swz;
#pragma unroll
    for (int n = 0; n < 2; ++n) ib[n] = (wn * 32 + n * 16 + lr) * 32 + swz;

    const f32x4 Z4 = {0.f, 0.f, 0.f, 0.f};
    f32x4 aG[4][2], aU[4][2];
#pragma unroll
    for (int m = 0; m < 4; ++m)
#pragma unroll
        for (int n = 0; n < 2; ++n) { aG[m][n] = Z4; aU[m][n] = Z4; }

    W_LOAD(0);
    X_STAGE(0, 0);
    W_WRITE(0);
    __syncthreads();
    int cur = 0;
    const int NT = (H_DIM / 2) / KC;      // 32
    for (int t = 0; t < NT; ++t) {
        const bool more = (t + 1 < NT);
        if (more) {
            X_STAGE(cur ^ 1, t + 1);
            W_LOAD(t + 1);
            SCHED0();                     // pin load-issue before MFMA phase
        }
        {
            bf16x8 a0 = *(const bf16x8*)&Xs[cur][ix[0]];
            bf16x8 a1 = *(const bf16x8*)&Xs[cur][ix[1]];
            bf16x8 a2 = *(const bf16x8*)&Xs[cur][ix[2]];
            bf16x8 a3 = *(const bf16x8*)&Xs[cur][ix[3]];
            bf16x8 g0 = *(const bf16x8*)&Gs[cur][ib[0]];
            bf16x8 g1 = *(const bf16x8*)&Gs[cur][ib[1]];
            bf16x8 u0 = *(const bf16x8*)&Us[cur][ib[0]];
            bf16x8 u1 = *(const bf16x8*)&Us[cur][ib[1]];
            aG[0][0] = __builtin_amdgcn_mfma_f32_16x16x32_bf16(a0, g0, aG[0][0], 0, 0, 0);
            aG[0][1] = __builtin_amdgcn_mfma_f32_16x16x32_bf16(a0, g1, aG[0][1], 0, 0, 0);
            aG[1][0] = __builtin_amdgcn_mfma_f32_16x16x32_bf16(a1, g0, aG[1][0], 0, 0, 0);
            aG[1][1] = __builtin_amdgcn_mfma_f32_16x16x32_bf16(a1, g1, aG[1][1], 0, 0, 0);
            aG[2][0] = __builtin_amdgcn_mfma_f32_16x16x32_bf16(a2, g0, aG[2][0], 0, 0, 0);
            aG[2][1] = __builtin_amdgcn_mfma_f32_16x16x32_bf16(a2, g1, aG[2][1], 0, 0, 0);
            aG[3][0] = __builtin_amdgcn_mfma_f32_16x16x32_bf16(a3, g0, aG[3][0], 0, 0, 0);
            aG[3][1] = __builtin_amdgcn_mfma_f32_16x16x32_bf16(a3, g1, aG[3][1], 0, 0, 0);
            aU[0][0] = __builtin_amdgcn_mfma_f32_16x16x32_bf16(a0, u0, aU[0][0], 0, 0, 0);
            aU[0][1] = __builtin_amdgcn_mfma_f32_16x16x32_bf16(a0, u1, aU[0][1], 0, 0, 0);
            aU[1][0] = __builtin_amdgcn_mfma_f32_16x16x32_bf16(a1, u0, aU[1][0], 0, 0, 0);
            aU[1][1] = __builtin_amdgcn_mfma_f32_16x16x32_bf16(a1, u1, aU[1][1], 0, 0, 0);
            aU[2][0] = __builtin_amdgcn_mfma_f32_16x16x32_bf16(a2, u0, aU[2][0], 0, 0, 0);
            aU[2][1] = __builtin_amdgcn_mfma_f32_16x16x32_bf16(a2, u1, aU[2][1], 0, 0, 0);
            aU[3][0] = __builtin_amdgcn_mfma_f32_16x16x32_bf16(a3, u0, aU[3][0], 0, 0, 0);
            aU[3][1] = __builtin_amdgcn_mfma_f32_16x16x32_bf16(a3, u1, aU[3][1], 0, 0, 0);
        }
        if (more) W_WRITE(cur ^ 1);       // fp32 load waits land here, after MFMA phase
        __syncthreads();
        cur ^= 1;
    }
#undef X_STAGE
#undef W_LOAD
#undef W_WRITE

    // epilogue: raw partial G/U sums (SwiGLU deferred to the sum pass)
    float* gp = gu_part + (size_t)kspl * SLOTS * TWO_I;
#pragma unroll
    for (int m = 0; m < 4; ++m)
#pragma unroll
        for (int n = 0; n < 2; ++n) {
            int col = i0 + wn * 32 + n * 16 + lr;
            int sbase = row0 + wm * 64 + m * 16 + lg * 4;
#pragma unroll
            for (int q = 0; q < 4; ++q) {
                gp[(size_t)(sbase + q) * TWO_I + col]         = aG[m][n][q];
                gp[(size_t)(sbase + q) * TWO_I + I_DIM + col] = aU[m][n][q];
            }
        }
}

// ---------------- sum partials + SwiGLU -> act bf16 ----------------
__global__ __launch_bounds__(256) void swiglu_pass(
    const float* __restrict__ gu_part, u16* __restrict__ act)
{
    int idx = blockIdx.x * 256 + threadIdx.x;     // over SLOTS * I_DIM / 4 units
    int slot = idx >> 7;                          // /128 (I_DIM/4)
    int i4 = (idx & 127) << 2;
    const float* p0 = gu_part + (size_t)slot * TWO_I + i4;
    const float* p1 = p0 + (size_t)SLOTS * TWO_I;
    float4 g0 = *(const float4*)p0;
    float4 g1 = *(const float4*)p1;
    float4 u0 = *(const float4*)(p0 + I_DIM);
    float4 u1 = *(const float4*)(p1 + I_DIM);
    float4 r;
    {
        float g = fminf(g0.x + g1.x, SWIGLU_LIMIT);
        float u = fminf(fmaxf(u0.x + u1.x, -SWIGLU_LIMIT), SWIGLU_LIMIT);
        r.x = g * (1.f / (1.f + __expf(-g))) * u;
    }
    {
        float g = fminf(g0.y + g1.y, SWIGLU_LIMIT);
        float u = fminf(fmaxf(u0.y + u1.y, -SWIGLU_LIMIT), SWIGLU_LIMIT);
        r.y = g * (1.f / (1.f + __expf(-g))) * u;
    }
    {
        float g = fminf(g0.z + g1.z, SWIGLU_LIMIT);
        float u = fminf(fmaxf(u0.z + u1.z, -SWIGLU_LIMIT), SWIGLU_LIMIT);
        r.z = g * (1.f / (1.f + __expf(-g))) * u;
    }
    {
        float g = fminf(g0.w + g1.w, SWIGLU_LIMIT);
        float u = fminf(fmaxf(u0.w + u1.w, -SWIGLU_LIMIT), SWIGLU_LIMIT);
        r.w = g * (1.f / (1.f + __expf(-g))) * u;
    }
    *(ushort4*)(act + (size_t)slot * I_DIM + i4) = pack4(r);
}

// ---------------- GEMM2: act(128x32 gload_lds) @ w2(128 rows reg-staged)^T * comb ----------------
// grid 768: y = (b&7)*2 + ((b>>3)&1) in [0,16), tile = b>>4
__global__ __launch_bounds__(256, 3) void gemm2_scatter(
    const u16* __restrict__ act, const float* __restrict__ w2,
    const int* __restrict__ A_tok, const float* __restrict__ A_w,
    const int* __restrict__ tile_e, const int* __restrict__ tile_r0,
    float* __restrict__ out)
{
    int b = blockIdx.x;
    int y = (b & 7) * 2 + ((b >> 3) & 1);
    int tile = b >> 4;
    int e = tile_e[tile];
    if (e < 0) return;
    int row0 = tile_r0[tile];
    int h0 = y * 128;
    int tid = threadIdx.x;

    __shared__ u16 As[2][4096];   // 128 x 32 bf16
    __shared__ u16 Bs[2][4096];   // 128 x 32 bf16

    const int l = tid & 63, w = tid >> 6;

    const u16* sA[2]; int dA[2];
#pragma unroll
    for (int j = 0; j < 2; ++j) {
        int row = w * 32 + j * 16 + (l >> 2);
        int sg = (l & 3) ^ ((l >> 3) & 3);
        sA[j] = act + (size_t)(row0 + row) * I_DIM + sg * 8;
        dA[j] = (w * 32 + j * 16) * 32;
    }
#define A_STAGE(bb, t) do { int ko = (t) * KC; \
    gload16(sA[0] + ko, &As[bb][dA[0]]); gload16(sA[1] + ko, &As[bb][dA[1]]); } while (0)

    // weight rows 128: thread t covers row t>>1, granules (t&1)*2 + {0,1}
    const int wr = tid >> 1;
    const int wg0 = (tid & 1) * 2;
    const float* bsrc = w2 + ((size_t)e * H_DIM + h0 + wr) * I_DIM;
    const int sk0 = ((wg0)     ^ ((wr >> 1) & 3)) * 8;
    const int sk1 = ((wg0 + 1) ^ ((wr >> 1) & 3)) * 8;
    const int wd0 = wr * 32 + wg0 * 8;

    float4 b0a, b0b, b1a, b1b;
#define B_LOAD(t) do { int ko = (t) * KC; \
    b0a = *(const float4*)(bsrc + ko + sk0); b0b = *(const float4*)(bsrc + ko + sk0 + 4); \
    b1a = *(const float4*)(bsrc + ko + sk1); b1b = *(const float4*)(bsrc + ko + sk1 + 4); } while (0)
#define B_WRITE(bb) do { \
    *(bf16x8*)&Bs[bb][wd0]     = cvt8(b0a, b0b); \
    *(bf16x8*)&Bs[bb][wd0 + 8] = cvt8(b1a, b1b); } while (0)

    // 4 waves 2x2; wave tile 64 slots x 64 cols; 4m x 4n frags
    const int wm = w >> 1, wn = w & 1;
    const int lr = l & 15, lg = l >> 4;
    const int swz = (lg ^ ((lr >> 1) & 3)) * 8;
    int ix[4], ib[4];
#pragma unroll
    for (int m = 0; m < 4; ++m) ix[m] = (wm * 64 + m * 16 + lr) * 32 + swz;
#pragma unroll
    for (int n = 0; n < 4; ++n) ib[n] = (wn * 64 + n * 16 + lr) * 32 + swz;

    const f32x4 Z4 = {0.f, 0.f, 0.f, 0.f};
    f32x4 acc[4][4];
#pragma unroll
    for (int m = 0; m < 4; ++m)
#pragma unroll
        for (int n = 0; n < 4; ++n) acc[m][n] = Z4;

    B_LOAD(0);
    A_STAGE(0, 0);
    B_WRITE(0);
    __syncthreads();
    int cur = 0;
    const int NT = I_DIM / KC;            // 16
    for (int t = 0; t < NT; ++t) {
        const bool more = (t + 1 < NT);
        if (more) {
            A_STAGE(cur ^ 1, t + 1);
            B_LOAD(t + 1);
            SCHED0();
        }
        {
            bf16x8 a[4], bb[4];
#pragma unroll
            for (int m = 0; m < 4; ++m) a[m] = *(const bf16x8*)&As[cur][ix[m]];
#pragma unroll
            for (int n = 0; n < 4; ++n) bb[n] = *(const bf16x8*)&Bs[cur][ib[n]];
#pragma unroll
            for (int m = 0; m < 4; ++m)
#pragma unroll
                for (int n = 0; n < 4; ++n)
                    acc[m][n] = __builtin_amdgcn_mfma_f32_16x16x32_bf16(a[m], bb[n], acc[m][n], 0, 0, 0);
        }
        if (more) B_WRITE(cur ^ 1);
        __syncthreads();
        cur ^= 1;
    }
#undef A_STAGE
#undef B_LOAD
#undef B_WRITE

#pragma unroll
    for (int m = 0; m < 4; ++m)
#pragma unroll
        for (int n = 0; n < 4; ++n) {
            int col = h0 + wn * 64 + n * 16 + lr;
            int sbase = row0 + wm * 64 + m * 16 + lg * 4;
#pragma unroll
            for (int q = 0; q < 4; ++q) {
                int slot = sbase + q;
                int tok = A_tok[slot];
                if (tok >= 0)
                    atomicAdd(&out[(size_t)tok * H_DIM + col], acc[m][n][q] * A_w[slot]);
            }
        }
}

extern "C" void kernel_launch(void* const* d_in, const int* in_sizes, int n_in,
                              void* d_out, int out_size, void* d_ws, size_t ws_size,
                              hipStream_t stream) {
    const float* hs   = (const float*)d_in[0];
    const float* gw   = (const float*)d_in[1];
    const float* bias = (const float*)d_in[2];
    const float* w13  = (const float*)d_in[3];
    const float* w2   = (const float*)d_in[4];
    float* out = (float*)d_out;

    char* ws = (char*)d_ws;
    int*   cnt      = (int*)(ws + 0);          // 64 B
    int*   tile_e   = (int*)(ws + 64);         // 192 B
    int*   tile_r0  = (int*)(ws + 320);        // 192 B (region to 1024)
    int*   tok_list = (int*)(ws + 1024);       // 131072 -> 132096
    float* w_list   = (float*)(ws + 132096);   // 131072 -> 263168
    int*   A_tok    = (int*)(ws + 263168);     // 24576  -> 287744
    float* A_w      = (float*)(ws + 287744);   // 24576  -> 312320
    u16*   act      = (u16*)(ws + 315392);     // 6291456 -> 6606848
    u16*   hs_bf    = (u16*)(ws + 6606848);    // 8388608 -> 14995456
    float* gu_part  = (float*)(ws + 14995456); // 2*6144*1024*4 = 50331648 -> ~65.3 MB
    // round-4 bf-path probe confirmed ws_size >= 114 MB

    hipMemsetAsync(d_out, 0, (size_t)T_TOK * H_DIM * sizeof(float), stream);
    hipMemsetAsync(cnt, 0, 64, stream);

    router_kernel<<<T_TOK / 4, 256, 0, stream>>>(hs, gw, bias, cnt, tok_list, w_list, hs_bf);
    scatter_build<<<(E_EXP * T_TOK) / 256, 256, 0, stream>>>(cnt, tok_list, w_list, A_tok, A_w, tile_e, tile_r0);

    gemm1_gu<<<MAX_TILES * 8 * 2, 256, 0, stream>>>(hs_bf, w13, A_tok, tile_e, tile_r0, gu_part);
    swiglu_pass<<<SLOTS * I_DIM / 4 / 256, 256, 0, stream>>>(gu_part, act);
    gemm2_scatter<<<MAX_TILES * 16, 256, 0, stream>>>(act, w2, A_tok, A_w, tile_e, tile_r0, out);
}

// Round 9
// 185.356 us; speedup vs baseline: 1.1293x; 1.1293x over previous
//
#include <hip/hip_runtime.h>
#include <hip/hip_bf16.h>
#include <math.h>

#define T_TOK 2048
#define H_DIM 2048
#define E_EXP 16
#define I_DIM 512
#define TWO_I 1024
#define ROUTED_SCALE 1.5f
#define SWIGLU_LIMIT 7.0f

#define BM 64
#define KC 64
#define KC2 32
#define MAX_TILES 80

typedef __attribute__((ext_vector_type(8))) short bf16x8;
typedef __attribute__((ext_vector_type(4))) float f32x4;
typedef unsigned short u16;

__device__ inline u16 f2bf(float f) {
    return __builtin_bit_cast(u16, __float2bfloat16(f));
}
__device__ inline ushort4 pack4(float4 a) {
    ushort4 v;
    v.x = f2bf(a.x); v.y = f2bf(a.y); v.z = f2bf(a.z); v.w = f2bf(a.w);
    return v;
}
__device__ inline bf16x8 pack8(float4 a, float4 b) {
    bf16x8 v;
    v[0] = (short)f2bf(a.x); v[1] = (short)f2bf(a.y);
    v[2] = (short)f2bf(a.z); v[3] = (short)f2bf(a.w);
    v[4] = (short)f2bf(b.x); v[5] = (short)f2bf(b.y);
    v[6] = (short)f2bf(b.z); v[7] = (short)f2bf(b.w);
    return v;
}

// async 16B/lane global->LDS DMA
__device__ inline void gload16(const u16* g, u16* l) {
    __builtin_amdgcn_global_load_lds(
        (const __attribute__((address_space(1))) void*)(g),
        (__attribute__((address_space(3))) void*)(l), 16, 0, 0);
}
#define SCHED0() __builtin_amdgcn_sched_barrier(0)

// swizzled ushort index for 64-elem bf16 rows: logical (row,k) -> row*64 + (k ^ ((row&7)<<3))
#define SWZ(row, k) ((row) * 64 + ((k) ^ (((row) & 7) << 3)))

// ---------------- router: one wave per token; also emits hs in bf16 ----------------
__global__ __launch_bounds__(256) void router_kernel(
    const float* __restrict__ hs, const float* __restrict__ gw,
    const float* __restrict__ bias, int* cnt, int* tok_list, float* w_list,
    u16* __restrict__ hs_bf)
{
    int wave = threadIdx.x >> 6;
    int lane = threadIdx.x & 63;
    int t = blockIdx.x * 4 + wave;
    if (t >= T_TOK) return;
    const float* x = hs + (size_t)t * H_DIM;

    float acc[E_EXP];
#pragma unroll
    for (int e = 0; e < E_EXP; ++e) acc[e] = 0.f;

#pragma unroll 2
    for (int c = 0; c < 8; ++c) {
        int col = c * 256 + lane * 4;
        float4 xv = *(const float4*)(x + col);
        *(ushort4*)(hs_bf + (size_t)t * H_DIM + col) = pack4(xv);
#pragma unroll
        for (int e = 0; e < E_EXP; ++e) {
            float4 gv = *(const float4*)(gw + (size_t)e * H_DIM + col);
            acc[e] = fmaf(xv.x, gv.x, acc[e]);
            acc[e] = fmaf(xv.y, gv.y, acc[e]);
            acc[e] = fmaf(xv.z, gv.z, acc[e]);
            acc[e] = fmaf(xv.w, gv.w, acc[e]);
        }
    }
#pragma unroll
    for (int e = 0; e < E_EXP; ++e) {
        for (int m = 32; m >= 1; m >>= 1)
            acc[e] += __shfl_xor(acc[e], m, 64);
    }
    if (lane == 0) {
        float sc[E_EXP], bsc[E_EXP];
#pragma unroll
        for (int e = 0; e < E_EXP; ++e) {
            sc[e] = 1.f / (1.f + expf(-acc[e]));
            bsc[e] = sc[e] + bias[e];
        }
        int e0 = 0; float b0 = bsc[0];
#pragma unroll
        for (int e = 1; e < E_EXP; ++e) if (bsc[e] > b0) { b0 = bsc[e]; e0 = e; }
        int e1 = -1; float b1 = -1e30f;
#pragma unroll
        for (int e = 0; e < E_EXP; ++e) {
            if (e == e0) continue;
            if (bsc[e] > b1) { b1 = bsc[e]; e1 = e; }
        }
        float s0 = sc[e0], s1 = sc[e1];
        float inv = ROUTED_SCALE / (s0 + s1);
        int p0 = atomicAdd(&cnt[e0], 1);
        tok_list[e0 * T_TOK + p0] = t;
        w_list[e0 * T_TOK + p0] = s0 * inv;
        int p1 = atomicAdd(&cnt[e1], 1);
        tok_list[e1 * T_TOK + p1] = t;
        w_list[e1 * T_TOK + p1] = s1 * inv;
    }
}

// ---------------- fused: compact assignments + tile descriptors (BM=64) ----------------
__global__ void scatter_build(const int* __restrict__ cnt,
    const int* __restrict__ tok_list, const float* __restrict__ w_list,
    int* A_tok, float* A_w, int* tile_e, int* tile_r0)
{
    int c[E_EXP], offs[E_EXP + 1];
    offs[0] = 0;
#pragma unroll
    for (int e = 0; e < E_EXP; ++e) {
        c[e] = cnt[e];
        offs[e + 1] = offs[e] + ((c[e] + BM - 1) & ~(BM - 1));
    }
    int idx = blockIdx.x * 256 + threadIdx.x;
    int e = idx >> 11;
    int pos = idx & (T_TOK - 1);
    int ce = c[e];
    int pe = (ce + BM - 1) & ~(BM - 1);
    if (pos < ce) {
        A_tok[offs[e] + pos] = tok_list[idx];
        A_w[offs[e] + pos] = w_list[idx];
    } else if (pos < pe) {
        A_tok[offs[e] + pos] = -1;
        A_w[offs[e] + pos] = 0.f;
    }
    if (idx == 0) {
        int nt = 0;
        for (int ee = 0; ee < E_EXP; ++ee) {
            int ntile = (c[ee] + BM - 1) >> 6;
            for (int j = 0; j < ntile; ++j) {
                tile_e[nt] = ee;
                tile_r0[nt] = offs[ee] + j * BM;
                ++nt;
            }
        }
        for (; nt < MAX_TILES; ++nt) tile_e[nt] = -1;
    }
}

// ---------------- GEMM1 (round-5 proven): X(bf16 gload_lds) @ w13(fp32 reg-staged)^T ----------------
__global__ __launch_bounds__(256, 3) void gemm1_act(
    const u16* __restrict__ hs_bf, const float* __restrict__ w13,
    const int* __restrict__ A_tok, const int* __restrict__ tile_e,
    const int* __restrict__ tile_r0, u16* __restrict__ act)
{
    int b = blockIdx.x;
    int id = (b & 7) * 80 + (b >> 3);      // XCD-chunked bijective swizzle (640 = 8*80)
    int tile = id % MAX_TILES;
    int y = id / MAX_TILES;                // 0..7
    int e = tile_e[tile];
    if (e < 0) return;
    int row0 = tile_r0[tile];
    int i0 = y * 64;
    int tid = threadIdx.x;

    __shared__ u16 Xs[2][4096];
    __shared__ u16 Gs[2][4096];
    __shared__ u16 Us[2][4096];

    const int l = tid & 63, w = tid >> 6;

    // ---- X staging via global_load_lds (pre-swizzled source, linear dest) ----
    const int rlo = l >> 3;                // 0..7
    const int c8 = (l & 7) << 3;
    const int ksrc = c8 ^ (rlo << 3);
    const int rowA = w * 16 + rlo;
    const int rowB = rowA + 8;
    int tokA = A_tok[row0 + rowA]; if (tokA < 0) tokA = 0;   // pad rows masked via A_w=0
    int tokB = A_tok[row0 + rowB]; if (tokB < 0) tokB = 0;
    const u16* sXA = hs_bf + (size_t)tokA * H_DIM + ksrc;
    const u16* sXB = hs_bf + (size_t)tokB * H_DIM + ksrc;
    const int dA = w * 1024;

#define X_STAGE(bb, t) do { int ko = (t) * KC; \
    gload16(sXA + ko, &Xs[bb][dA]);  gload16(sXB + ko, &Xs[bb][dA + 512]); } while (0)

    // ---- weight staging: dense fp32 loads -> regs -> convert -> swizzled ds_write ----
    const int srow = tid >> 4;             // 0..15
    const int sc4  = tid & 15;
    const int kphys = (sc4 * 4) ^ ((srow & 7) << 3);
    const int sbase = srow * 64 + kphys;   // elem offset in LDS tile; +j*1024
    const float* gsrc = w13 + ((size_t)e * TWO_I + i0 + srow) * H_DIM + sc4 * 4;
    const float* usrc = gsrc + (size_t)I_DIM * H_DIM;

    float4 gld[4], uld[4];
#define W_LOAD(t) do { int k0 = (t) * KC; \
    gld[0] = *(const float4*)(gsrc + k0); \
    gld[1] = *(const float4*)(gsrc + k0 + 16 * H_DIM); \
    gld[2] = *(const float4*)(gsrc + k0 + 32 * H_DIM); \
    gld[3] = *(const float4*)(gsrc + k0 + 48 * H_DIM); \
    uld[0] = *(const float4*)(usrc + k0); \
    uld[1] = *(const float4*)(usrc + k0 + 16 * H_DIM); \
    uld[2] = *(const float4*)(usrc + k0 + 32 * H_DIM); \
    uld[3] = *(const float4*)(usrc + k0 + 48 * H_DIM); } while (0)

#define W_WRITE(bb) do { \
    *(ushort4*)&Gs[bb][sbase]        = pack4(gld[0]); \
    *(ushort4*)&Gs[bb][sbase + 1024] = pack4(gld[1]); \
    *(ushort4*)&Gs[bb][sbase + 2048] = pack4(gld[2]); \
    *(ushort4*)&Gs[bb][sbase + 3072] = pack4(gld[3]); \
    *(ushort4*)&Us[bb][sbase]        = pack4(uld[0]); \
    *(ushort4*)&Us[bb][sbase + 1024] = pack4(uld[1]); \
    *(ushort4*)&Us[bb][sbase + 2048] = pack4(uld[2]); \
    *(ushort4*)&Us[bb][sbase + 3072] = pack4(uld[3]); } while (0)

    // ---- MFMA roles: 4 waves as 2x2 over (token32, i32) ----
    const int wm = w >> 1, wn = w & 1;
    const int lr = l & 15;
    const int lg = l >> 4;
    const int ra0 = wm * 32 + lr, ra1 = ra0 + 16;
    const int rb0 = wn * 32 + lr, rb1 = rb0 + 16;
    int ia0[2], ia1[2], ib0[2], ib1[2];
#pragma unroll
    for (int kh = 0; kh < 2; ++kh) {
        int e2 = kh * 32 + lg * 8;
        ia0[kh] = SWZ(ra0, e2); ia1[kh] = SWZ(ra1, e2);
        ib0[kh] = SWZ(rb0, e2); ib1[kh] = SWZ(rb1, e2);
    }

    const f32x4 Z4 = {0.f, 0.f, 0.f, 0.f};
    f32x4 aG[2][2], aU[2][2];
#pragma unroll
    for (int m = 0; m < 2; ++m)
#pragma unroll
        for (int n = 0; n < 2; ++n) { aG[m][n] = Z4; aU[m][n] = Z4; }

    W_LOAD(0);
    X_STAGE(0, 0);
    W_WRITE(0);
    __syncthreads();
    int cur = 0;
    const int NT = H_DIM / KC;             // 32
    for (int t = 0; t < NT; ++t) {
        const bool more = (t + 1 < NT);
        if (more) {
            X_STAGE(cur ^ 1, t + 1);
            W_LOAD(t + 1);
            SCHED0();                      // pin load-issue before MFMA phase
        }
#pragma unroll
        for (int kh = 0; kh < 2; ++kh) {
            bf16x8 a0 = *(const bf16x8*)&Xs[cur][ia0[kh]];
            bf16x8 a1 = *(const bf16x8*)&Xs[cur][ia1[kh]];
            bf16x8 g0 = *(const bf16x8*)&Gs[cur][ib0[kh]];
            bf16x8 g1 = *(const bf16x8*)&Gs[cur][ib1[kh]];
            bf16x8 u0 = *(const bf16x8*)&Us[cur][ib0[kh]];
            bf16x8 u1 = *(const bf16x8*)&Us[cur][ib1[kh]];
            aG[0][0] = __builtin_amdgcn_mfma_f32_16x16x32_bf16(a0, g0, aG[0][0], 0, 0, 0);
            aG[0][1] = __builtin_amdgcn_mfma_f32_16x16x32_bf16(a0, g1, aG[0][1], 0, 0, 0);
            aG[1][0] = __builtin_amdgcn_mfma_f32_16x16x32_bf16(a1, g0, aG[1][0], 0, 0, 0);
            aG[1][1] = __builtin_amdgcn_mfma_f32_16x16x32_bf16(a1, g1, aG[1][1], 0, 0, 0);
            aU[0][0] = __builtin_amdgcn_mfma_f32_16x16x32_bf16(a0, u0, aU[0][0], 0, 0, 0);
            aU[0][1] = __builtin_amdgcn_mfma_f32_16x16x32_bf16(a0, u1, aU[0][1], 0, 0, 0);
            aU[1][0] = __builtin_amdgcn_mfma_f32_16x16x32_bf16(a1, u0, aU[1][0], 0, 0, 0);
            aU[1][1] = __builtin_amdgcn_mfma_f32_16x16x32_bf16(a1, u1, aU[1][1], 0, 0, 0);
        }
        if (more) W_WRITE(cur ^ 1);        // fp32 load waits land here, after MFMA phase
        __syncthreads();
        cur ^= 1;
    }
#undef X_STAGE
#undef W_LOAD
#undef W_WRITE

#pragma unroll
    for (int m = 0; m < 2; ++m)
#pragma unroll
        for (int n = 0; n < 2; ++n) {
            int col = i0 + wn * 32 + n * 16 + lr;
            int rbase = row0 + wm * 32 + m * 16 + lg * 4;
#pragma unroll
            for (int q = 0; q < 4; ++q) {
                float g = fminf(aG[m][n][q], SWIGLU_LIMIT);
                float u = fminf(fmaxf(aU[m][n][q], -SWIGLU_LIMIT), SWIGLU_LIMIT);
                float s = 1.f / (1.f + __expf(-g));
                act[(size_t)(rbase + q) * I_DIM + col] = f2bf(g * s * u);
            }
        }
}

// ---------------- GEMM2: BM=64, BN=128, KC2=32 -> 1088 active blocks (4.25/CU) ----------------
__global__ __launch_bounds__(256, 4) void gemm2_scatter(
    const u16* __restrict__ act, const float* __restrict__ w2,
    const int* __restrict__ A_tok, const float* __restrict__ A_w,
    const int* __restrict__ tile_e, const int* __restrict__ tile_r0,
    float* __restrict__ out)
{
    int b = blockIdx.x;
    int id = (b & 7) * 160 + (b >> 3);     // 1280 = 8*160; XCD x owns y in {2x,2x+1}
    int tile = id % MAX_TILES;
    int y = id / MAX_TILES;                // 0..15
    int e = tile_e[tile];
    if (e < 0) return;
    int row0 = tile_r0[tile];
    int h0 = y * 128;
    int tid = threadIdx.x;

    __shared__ u16 As[2][2048];            // 64 x 32 bf16
    __shared__ u16 Bs[2][4096];            // 128 x 32 bf16

    const int l = tid & 63, w = tid >> 6;

    // ---- act staging via gload_lds: wave w covers rows w*16 + (l>>2) ----
    {
    }
    const int arow = w * 16 + (l >> 2);
    const int sg = (l & 3) ^ ((l >> 3) & 3);
    const u16* sA = act + (size_t)(row0 + arow) * I_DIM + sg * 8;
    const int dA = w * 512;

#define A_STAGE(bb, t) do { int ko = (t) * KC2; \
    gload16(sA + ko, &As[bb][dA]); } while (0)

    // ---- w2 staging: thread t covers row t>>1, 16-col half (t&1); swizzled ds_write ----
    const int wr = tid >> 1;               // 0..127
    const int g0 = (tid & 1) * 2;          // granule pair
    const int g1 = g0 + 1;
    const float* bsrc = w2 + ((size_t)e * H_DIM + h0 + wr) * I_DIM + g0 * 8;
    const int wswz = (wr >> 1) & 3;
    const int wd0 = wr * 32 + (g0 ^ wswz) * 8;
    const int wd1 = wr * 32 + (g1 ^ wswz) * 8;

    float4 b0a, b0b, b1a, b1b;
#define B_LOAD(t) do { int ko = (t) * KC2; \
    b0a = *(const float4*)(bsrc + ko);      b0b = *(const float4*)(bsrc + ko + 4); \
    b1a = *(const float4*)(bsrc + ko + 8);  b1b = *(const float4*)(bsrc + ko + 12); } while (0)
#define B_WRITE(bb) do { \
    *(bf16x8*)&Bs[bb][wd0] = pack8(b0a, b0b); \
    *(bf16x8*)&Bs[bb][wd1] = pack8(b1a, b1b); } while (0)

    // ---- MFMA roles: 4 waves 2x2; wave tile 32 slots x 64 cols; 2m x 4n frags ----
    const int wm = w >> 1, wn = w & 1;
    const int lr = l & 15, lg = l >> 4;
    const int swz = (lg ^ ((lr >> 1) & 3)) * 8;
    int ix[2], ib[4];
#pragma unroll
    for (int m = 0; m < 2; ++m) ix[m] = (wm * 32 + m * 16 + lr) * 32 + swz;
#pragma unroll
    for (int n = 0; n < 4; ++n) ib[n] = (wn * 64 + n * 16 + lr) * 32 + swz;

    const f32x4 Z4 = {0.f, 0.f, 0.f, 0.f};
    f32x4 acc[2][4];
#pragma unroll
    for (int m = 0; m < 2; ++m)
#pragma unroll
        for (int n = 0; n < 4; ++n) acc[m][n] = Z4;

    B_LOAD(0);
    A_STAGE(0, 0);
    B_WRITE(0);
    __syncthreads();
    int cur = 0;
    const int NT = I_DIM / KC2;            // 16
    for (int t = 0; t < NT; ++t) {
        const bool more = (t + 1 < NT);
        if (more) {
            A_STAGE(cur ^ 1, t + 1);
            B_LOAD(t + 1);
            SCHED0();
        }
        {
            bf16x8 a0 = *(const bf16x8*)&As[cur][ix[0]];
            bf16x8 a1 = *(const bf16x8*)&As[cur][ix[1]];
            bf16x8 v0 = *(const bf16x8*)&Bs[cur][ib[0]];
            bf16x8 v1 = *(const bf16x8*)&Bs[cur][ib[1]];
            bf16x8 v2 = *(const bf16x8*)&Bs[cur][ib[2]];
            bf16x8 v3 = *(const bf16x8*)&Bs[cur][ib[3]];
            acc[0][0] = __builtin_amdgcn_mfma_f32_16x16x32_bf16(a0, v0, acc[0][0], 0, 0, 0);
            acc[0][1] = __builtin_amdgcn_mfma_f32_16x16x32_bf16(a0, v1, acc[0][1], 0, 0, 0);
            acc[0][2] = __builtin_amdgcn_mfma_f32_16x16x32_bf16(a0, v2, acc[0][2], 0, 0, 0);
            acc[0][3] = __builtin_amdgcn_mfma_f32_16x16x32_bf16(a0, v3, acc[0][3], 0, 0, 0);
            acc[1][0] = __builtin_amdgcn_mfma_f32_16x16x32_bf16(a1, v0, acc[1][0], 0, 0, 0);
            acc[1][1] = __builtin_amdgcn_mfma_f32_16x16x32_bf16(a1, v1, acc[1][1], 0, 0, 0);
            acc[1][2] = __builtin_amdgcn_mfma_f32_16x16x32_bf16(a1, v2, acc[1][2], 0, 0, 0);
            acc[1][3] = __builtin_amdgcn_mfma_f32_16x16x32_bf16(a1, v3, acc[1][3], 0, 0, 0);
        }
        if (more) B_WRITE(cur ^ 1);
        __syncthreads();
        cur ^= 1;
    }
#undef A_STAGE
#undef B_LOAD
#undef B_WRITE

    // epilogue: per-slot combine weight from global
#pragma unroll
    for (int m = 0; m < 2; ++m)
#pragma unroll
        for (int n = 0; n < 4; ++n) {
            int col = h0 + wn * 64 + n * 16 + lr;
            int sbase = wm * 32 + m * 16 + lg * 4;
#pragma unroll
            for (int q = 0; q < 4; ++q) {
                int slot = row0 + sbase + q;
                int tok = A_tok[slot];
                if (tok >= 0)
                    atomicAdd(&out[(size_t)tok * H_DIM + col], acc[m][n][q] * A_w[slot]);
            }
        }
}

extern "C" void kernel_launch(void* const* d_in, const int* in_sizes, int n_in,
                              void* d_out, int out_size, void* d_ws, size_t ws_size,
                              hipStream_t stream) {
    const float* hs   = (const float*)d_in[0];
    const float* gw   = (const float*)d_in[1];
    const float* bias = (const float*)d_in[2];
    const float* w13  = (const float*)d_in[3];
    const float* w2   = (const float*)d_in[4];
    float* out = (float*)d_out;

    char* ws = (char*)d_ws;
    int*   cnt      = (int*)(ws + 0);
    int*   tile_e   = (int*)(ws + 64);
    int*   tile_r0  = (int*)(ws + 384);
    int*   tok_list = (int*)(ws + 1024);
    float* w_list   = (float*)(ws + 132096);
    int*   A_tok    = (int*)(ws + 263168);
    float* A_w      = (float*)(ws + 283648);
    u16*   act      = (u16*)(ws + 304128);       // 5 MB
    u16*   hs_bf    = (u16*)(ws + 5547008);      // 8 MB -> ~13.6 MB total

    hipMemsetAsync(d_out, 0, (size_t)T_TOK * H_DIM * sizeof(float), stream);
    hipMemsetAsync(cnt, 0, 64, stream);

    router_kernel<<<T_TOK / 4, 256, 0, stream>>>(hs, gw, bias, cnt, tok_list, w_list, hs_bf);
    scatter_build<<<(E_EXP * T_TOK) / 256, 256, 0, stream>>>(cnt, tok_list, w_list, A_tok, A_w, tile_e, tile_r0);

    gemm1_act<<<MAX_TILES * 8, 256, 0, stream>>>(hs_bf, w13, A_tok, tile_e, tile_r0, act);
    gemm2_scatter<<<MAX_TILES * 16, 256, 0, stream>>>(act, w2, A_tok, A_w, tile_e, tile_r0, out);
}